// Round 4
// baseline (2241.918 us; speedup 1.0000x reference)
//
#include <hip/hip_runtime.h>

#define NSTEPS 20

// Tiny MLP: 4 -> 30 -> 5 -> 30 -> 5 -> 30 -> 2, returns output column COL.
// k-outer loop order: every weight access walks a CONSECUTIVE f32 run
// (s_load_dwordx4/x8-friendly, wave-uniform -> scalar pipe). Per-output
// summation order is unchanged vs the validated round-1 kernel (k ascending),
// so the arithmetic is bit-identical to the version that passed at absmax 0.5.
template<int COL>
__device__ __forceinline__ float evalnet(
    float f0, float f1, float f2, float f3,
    const float* __restrict__ W1, const float* __restrict__ b1,
    const float* __restrict__ W2, const float* __restrict__ b2,
    const float* __restrict__ W3, const float* __restrict__ b3,
    const float* __restrict__ W4, const float* __restrict__ b4,
    const float* __restrict__ W5, const float* __restrict__ b5,
    const float* __restrict__ W6, const float* __restrict__ b6)
{
    // ---- L1: 4 -> 30 (relu) ----
    float h1[30];
#pragma unroll
    for (int j = 0; j < 30; ++j) h1[j] = b1[j];
#pragma unroll
    for (int j = 0; j < 30; ++j) h1[j] = fmaf(f0, W1[0 * 30 + j], h1[j]);
#pragma unroll
    for (int j = 0; j < 30; ++j) h1[j] = fmaf(f1, W1[1 * 30 + j], h1[j]);
#pragma unroll
    for (int j = 0; j < 30; ++j) h1[j] = fmaf(f2, W1[2 * 30 + j], h1[j]);
#pragma unroll
    for (int j = 0; j < 30; ++j) h1[j] = fmaf(f3, W1[3 * 30 + j], h1[j]);
#pragma unroll
    for (int j = 0; j < 30; ++j) h1[j] = fmaxf(h1[j], 0.0f);

    // ---- L2: 30 -> 5 ----
    float h2[5];
#pragma unroll
    for (int c = 0; c < 5; ++c) h2[c] = b2[c];
#pragma unroll
    for (int k = 0; k < 30; ++k) {
#pragma unroll
        for (int c = 0; c < 5; ++c) h2[c] = fmaf(h1[k], W2[k * 5 + c], h2[c]);
    }

    // ---- L3: 5 -> 30 (relu) ----
    float h3[30];
#pragma unroll
    for (int j = 0; j < 30; ++j) h3[j] = b3[j];
#pragma unroll
    for (int k = 0; k < 5; ++k) {
#pragma unroll
        for (int j = 0; j < 30; ++j) h3[j] = fmaf(h2[k], W3[k * 30 + j], h3[j]);
    }
#pragma unroll
    for (int j = 0; j < 30; ++j) h3[j] = fmaxf(h3[j], 0.0f);

    // ---- L4: 30 -> 5 ----
    float h4[5];
#pragma unroll
    for (int c = 0; c < 5; ++c) h4[c] = b4[c];
#pragma unroll
    for (int k = 0; k < 30; ++k) {
#pragma unroll
        for (int c = 0; c < 5; ++c) h4[c] = fmaf(h3[k], W4[k * 5 + c], h4[c]);
    }

    // ---- L5: 5 -> 30 (relu) ----
    float h5[30];
#pragma unroll
    for (int j = 0; j < 30; ++j) h5[j] = b5[j];
#pragma unroll
    for (int k = 0; k < 5; ++k) {
#pragma unroll
        for (int j = 0; j < 30; ++j) h5[j] = fmaf(h4[k], W5[k * 30 + j], h5[j]);
    }
#pragma unroll
    for (int j = 0; j < 30; ++j) h5[j] = fmaxf(h5[j], 0.0f);

    // ---- L6: 30 -> 2, only column COL needed ----
    float o = b6[COL];
#pragma unroll
    for (int k = 0; k < 30; ++k) o = fmaf(h5[k], W6[k * 2 + COL], o);
    return o;
}

// __launch_bounds__(256, 2): 2 waves/EU -> 256-VGPR budget. Round 1 ran at
// 100 VGPRs (default occupancy targeting) and showed ~4x VALU instruction
// bloat (allocator copies/remat under pressure). Give the allocator room.
__global__ __launch_bounds__(256, 2) void mc_hedge_kernel(
    const float* __restrict__ S0, const float* __restrict__ Kv,
    const float* __restrict__ Tv, const float* __restrict__ BM,
    const float* __restrict__ W1, const float* __restrict__ b1,
    const float* __restrict__ W2, const float* __restrict__ b2,
    const float* __restrict__ W3, const float* __restrict__ b3,
    const float* __restrict__ W4, const float* __restrict__ b4,
    const float* __restrict__ W5, const float* __restrict__ b5,
    const float* __restrict__ W6, const float* __restrict__ b6,
    float* __restrict__ out, int Btot)
{
    const int i = blockIdx.x * blockDim.x + threadIdx.x;
    if (i >= Btot) return;

    float price = S0[i];
    const float Kk = Kv[i];
    const float T  = Tv[i];
    const float logK = __logf(Kk);
    float hedge = 0.0f;

    // Preload the 20 Brownian increments (80 B, 16B-aligned rows).
    float bm[NSTEPS];
    {
        const float* row = BM + (size_t)i * NSTEPS;
#pragma unroll
        for (int t = 0; t < NSTEPS; t += 4) {
            const float4 v = *reinterpret_cast<const float4*>(row + t);
            bm[t] = v.x; bm[t + 1] = v.y; bm[t + 2] = v.z; bm[t + 3] = v.w;
        }
    }

#pragma unroll 1
    for (int idx = 0; idx < NSTEPS; ++idx) {
        // exact division so time==0.5 / ==1.0 compare bit-exactly vs reference
        const float time = (float)(idx + 1) / (float)NSTEPS;
        const float do_comp = (time <= T) ? 1.0f : 0.0f;
        const float inc = bm[idx] * (1.0f / (float)NSTEPS);
        const float Tmt = T - time;

        // eval 1: leverage = net(feats(price_old))[0]
        float lp = __logf(price) - logK;
        const float lev = evalnet<0>(price, time, Tmt, lp,
                                     W1, b1, W2, b2, W3, b3, W4, b4, W5, b5, W6, b6);
        price = price + do_comp * lev * price * inc;

        // eval 2: hedge increment = net(feats(price_new))[1] * inc
        lp = __logf(price) - logK;
        const float hed = evalnet<1>(price, time, Tmt, lp,
                                     W1, b1, W2, b2, W3, b3, W4, b4, W5, b5, W6, b6) * inc;
        hedge = hedge + do_comp * hed;
    }

    const float payoff = fmaxf(price - Kk, 0.0f);
    out[i] = payoff - hedge;
}

extern "C" void kernel_launch(void* const* d_in, const int* in_sizes, int n_in,
                              void* d_out, int out_size, void* d_ws, size_t ws_size,
                              hipStream_t stream)
{
    const float* S0 = (const float*)d_in[0];
    const float* Kv = (const float*)d_in[1];
    const float* Tv = (const float*)d_in[2];
    const float* BM = (const float*)d_in[3];
    const float* W1 = (const float*)d_in[4];
    const float* b1 = (const float*)d_in[5];
    const float* W2 = (const float*)d_in[6];
    const float* b2 = (const float*)d_in[7];
    const float* W3 = (const float*)d_in[8];
    const float* b3 = (const float*)d_in[9];
    const float* W4 = (const float*)d_in[10];
    const float* b4 = (const float*)d_in[11];
    const float* W5 = (const float*)d_in[12];
    const float* b5 = (const float*)d_in[13];
    const float* W6 = (const float*)d_in[14];
    const float* b6 = (const float*)d_in[15];

    float* out = (float*)d_out;
    const int B = in_sizes[0];
    const int block = 256;
    const int grid = (B + block - 1) / block;

    mc_hedge_kernel<<<grid, block, 0, stream>>>(
        S0, Kv, Tv, BM,
        W1, b1, W2, b2, W3, b3, W4, b4, W5, b5, W6, b6,
        out, B);
}

// Round 7
// 1929.100 us; speedup vs baseline: 1.1622x; 1.1622x over previous
//
#include <hip/hip_runtime.h>

#define NSTEPS 20

typedef short bf16x8 __attribute__((ext_vector_type(8)));
typedef float f32x16 __attribute__((ext_vector_type(16)));

union B8 { bf16x8 h; unsigned u[4]; unsigned short s[8]; };

// RNE f32 -> bf16 bits (scalar; weight prep + rare paths)
__device__ __forceinline__ unsigned short f2bf(float x) {
    unsigned u = __builtin_bit_cast(unsigned, x);
    u += 0x7fffu + ((u >> 16) & 1u);
    return (unsigned short)(u >> 16);
}
__device__ __forceinline__ float bf2f(unsigned short b) {
    return __builtin_bit_cast(float, (unsigned)b << 16);
}
__device__ __forceinline__ unsigned pk(unsigned short lo, unsigned short hi) {
    return (unsigned)lo | ((unsigned)hi << 16);
}
// packed cvt: (a,b) -> bf16(a) | bf16(b)<<16   (HW instr; rounding self-corrected by limbs)
__device__ __forceinline__ unsigned cvtpk(float a, float b) {
    unsigned r;
    asm("v_cvt_pk_bf16_f32 %0, %1, %2" : "=v"(r) : "v"(a), "v"(b));
    return r;
}
__device__ __forceinline__ float lo_f(unsigned w) { return __builtin_bit_cast(float, w << 16); }
__device__ __forceinline__ float hi_f(unsigned w) { return __builtin_bit_cast(float, w & 0xffff0000u); }

#define MFMA(A, B, C) __builtin_amdgcn_mfma_f32_32x32x16_bf16((A), (B), (C), 0, 0, 0)

// 3-limb split of w (exact to ~2^-26 relative; bf16 => never denormal)
__device__ __forceinline__ void wlimbs(float w, unsigned short& l0, unsigned short& l1, unsigned short& l2) {
    l0 = f2bf(w); float e = w - bf2f(l0);
    l1 = f2bf(e); e -= bf2f(l1);
    l2 = f2bf(e);
}
__device__ __forceinline__ unsigned short pick(int m, unsigned short l0, unsigned short l1, unsigned short l2) {
    return (m == 0) ? l0 : ((m == 1) ? l1 : l2);
}

// ---------- A-fragment builders; k = 16f + 4h + (j&3) + 8*(j>>2) ----------

// 30-input layers (L2/L4/L6): limb m of W at k<30; limb m of bias at k30; 0 at k31.
__device__ bf16x8 awide(const float* W, const float* bias, int nout, int ld,
                        int f, int m, int lane)
{
    const int u = lane & 31, h = (lane >> 5) & 1;
    B8 r;
    for (int j = 0; j < 8; ++j) {
        const int k = 16 * f + 4 * h + (j & 3) + 8 * (j >> 2);
        float v = 0.f;
        if (u < nout) {
            if (k < 30) v = W[k * ld + u];
            else if (k == 30) v = bias[u];
        }
        unsigned short l0, l1, l2; wlimbs(v, l0, l1, l2);
        r.s[j] = (short)pick(m, l0, l1, l2);
    }
    return r.h;
}

// 5-input layers (L3/L5). B slot map:
//  frag0: k0-3 = a0(in0-3), k4 = a0(in4), k15 = bias-one; else 0
//  frag1: k16-19 = a1(in0-3), k20 = a1(in4), k24-27 = a2(in0-3), k21 = a2(in4); else 0
// A-set s: a0-slots get w-limb s; a1-slots: {s0->l1, s1->l0, s2->none};
//          a2-slots: {s0->l2, s1->none, s2->l0}; bias k15 gets bias-limb s.
// Sum over s: w*a covers all limb products i+j<=2 (+ harmless 2,2).
__device__ bf16x8 a5(const float* W, const float* bias, int s, int f, int lane)
{
    const int u = lane & 31, h = (lane >> 5) & 1;
    B8 r;
    for (int j = 0; j < 8; ++j) {
        const int k = 16 * f + 4 * h + (j & 3) + 8 * (j >> 2);
        unsigned short bits = 0;
        if (u < 30) {
            int in = -1, m = -1;
            if (f == 0) {
                if (k < 4)       { in = k; m = s; }
                else if (k == 4) { in = 4; m = s; }
            } else {
                if (k >= 16 && k < 20)      { in = k - 16; m = (s == 0) ? 1 : ((s == 1) ? 0 : -1); }
                else if (k == 20)           { in = 4;      m = (s == 0) ? 1 : ((s == 1) ? 0 : -1); }
                else if (k >= 24 && k < 28) { in = k - 24; m = (s == 0) ? 2 : ((s == 2) ? 0 : -1); }
                else if (k == 21)           { in = 4;      m = (s == 0) ? 2 : ((s == 2) ? 0 : -1); }
            }
            if (in >= 0 && m >= 0) {
                unsigned short l0, l1, l2; wlimbs(W[in * 30 + u], l0, l1, l2);
                bits = pick(m, l0, l1, l2);
            } else if (f == 0 && k == 15) {
                unsigned short l0, l1, l2; wlimbs(bias[u], l0, l1, l2);
                bits = pick(s, l0, l1, l2);
            }
        }
        r.s[j] = (short)bits;
    }
    return r.h;
}

// L1. Feature order (price, f3, t, T-t) -> W1 rows perm {0,3,1,2}.
// B slots: k0-3 = feat a0, k4-7 = feat a1, k8-11 = feat a2, k12 = bias-one.
__device__ bf16x8 a1f(const float* W1, const float* b1v, int s, int lane)
{
    const int perm[4] = {0, 3, 1, 2};
    const int u = lane & 31, h = (lane >> 5) & 1;
    B8 r;
    for (int j = 0; j < 8; ++j) {
        const int k = 4 * h + (j & 3) + 8 * (j >> 2);
        unsigned short bits = 0;
        if (u < 30) {
            int in = -1, m = -1;
            if (k < 4)       { in = k;     m = (s == 0) ? 0 : ((s == 1) ? 1 : 2); }
            else if (k < 8)  { in = k - 4; m = (s == 0) ? 1 : ((s == 1) ? 0 : -1); }
            else if (k < 12) { in = k - 8; m = (s == 0) ? 2 : ((s == 2) ? 0 : -1); }
            if (in >= 0 && m >= 0) {
                unsigned short l0, l1, l2; wlimbs(W1[perm[in] * 30 + u], l0, l1, l2);
                bits = pick(m, l0, l1, l2);
            } else if (k == 12) {
                unsigned short l0, l1, l2; wlimbs(b1v[u], l0, l1, l2);
                bits = pick(s, l0, l1, l2);
            }
        }
        r.s[j] = (short)bits;
    }
    return r.h;
}

// ---------- activation transitions ----------

__device__ __forceinline__ void split_pair(float a, float b,
                                           unsigned& w0, unsigned& w1, unsigned& w2)
{
    w0 = cvtpk(a, b);
    float e0 = a - lo_f(w0), e1 = b - hi_f(w0);
    w1 = cvtpk(e0, e1);
    float f0 = e0 - lo_f(w1), f1 = e1 - hi_f(w1);
    w2 = cvtpk(f0, f1);
}

// 30-wide output -> 3 limb frag-pairs, WITH relu (L1/L3/L5 outputs are relu'd
// in the reference); bias-one slots on hi lanes (k30).
__device__ __forceinline__ void split30(const f32x16& acc, bool hi,
                                        B8 B0[2], B8 B1[2], B8 B2[2])
{
#pragma unroll
    for (int i = 0; i < 8; ++i) {
        const float a = fmaxf(acc[2 * i], 0.f), b = fmaxf(acc[2 * i + 1], 0.f);
        unsigned w0, w1, w2; split_pair(a, b, w0, w1, w2);
        B0[i >> 2].u[i & 3] = w0; B1[i >> 2].u[i & 3] = w1; B2[i >> 2].u[i & 3] = w2;
    }
    if (hi) { B0[1].u[3] = 0x00003F80u; B1[1].u[3] = 0u; B2[1].u[3] = 0u; }
}

// 5-wide output (units 0-3 on lo lanes, unit 4 = acc[0] on hi lanes).
// *** NO RELU *** — reference applies no nonlinearity to the 5-wide (L2/L4)
// outputs: h = relu(x@W1+b1) @ W2 + b2 goes straight into the next stack.
// (The relu here was the shared bug behind rounds 2/3/5/6's absmax 11.5.)
__device__ __forceinline__ void split5(const f32x16& acc, bool hi, B8& C0, B8& C1)
{
    const float a0 = acc[0], a1 = acc[1];
    const float a2 = acc[2], a3 = acc[3];
    unsigned p0, p1, p2, q0, q1, q2;
    split_pair(a0, a1, p0, p1, p2);
    split_pair(a2, a3, q0, q1, q2);
    if (!hi) {
        C0.u[0] = p0; C0.u[1] = q0; C0.u[2] = 0; C0.u[3] = 0;
        C1.u[0] = p1; C1.u[1] = q1; C1.u[2] = p2; C1.u[3] = q2;
    } else {
        C0.u[0] = p0 & 0xffffu;       // k4 = a0(u4), k5 = 0
        C0.u[1] = 0; C0.u[2] = 0;
        C0.u[3] = 0x3F800000u;        // k14 = 0, k15 = 1.0
        C1.u[0] = pk((unsigned short)(p1 & 0xffffu), (unsigned short)(p2 & 0xffffu)); // k20=a1u4, k21=a2u4
        C1.u[1] = 0; C1.u[2] = 0; C1.u[3] = 0;
    }
}

struct Frags {
    bf16x8 A1[3];
    bf16x8 A2[3][2];
    bf16x8 A3[3][2];
    bf16x8 A4[3][2];
    bf16x8 A5[3][2];
    bf16x8 A6[3][2];
};

__device__ __forceinline__ void evalnet(
    float price, float f3, unsigned tT0, unsigned tT1, unsigned tT2,
    bool hi, const Frags& F, const f32x16& Z, float& o0, float& o1)
{
    unsigned pf0, pf1, pf2;
    split_pair(price, f3, pf0, pf1, pf2);
    B8 B;
    if (!hi) { B.u[0] = pf0; B.u[1] = tT0; B.u[2] = pf2; B.u[3] = tT2; }
    else     { B.u[0] = pf1; B.u[1] = tT1; B.u[2] = 0x00003F80u; B.u[3] = 0u; }

    f32x16 acc = MFMA(F.A1[0], B.h, Z);
    acc = MFMA(F.A1[1], B.h, acc);
    acc = MFMA(F.A1[2], B.h, acc);

    B8 B0[2], B1l[2], B2[2], C0, C1;

    // L2: 30 -> 5 (no relu on output)
    split30(acc, hi, B0, B1l, B2);
    acc = MFMA(F.A2[0][0], B0[0].h, Z);    acc = MFMA(F.A2[0][1], B0[1].h, acc);   // w0*a0 (+b0)
    acc = MFMA(F.A2[0][0], B1l[0].h, acc); acc = MFMA(F.A2[0][1], B1l[1].h, acc);  // w0*a1
    acc = MFMA(F.A2[0][0], B2[0].h, acc);  acc = MFMA(F.A2[0][1], B2[1].h, acc);   // w0*a2
    acc = MFMA(F.A2[1][0], B0[0].h, acc);  acc = MFMA(F.A2[1][1], B0[1].h, acc);   // w1*a0 (+b1)
    acc = MFMA(F.A2[1][0], B1l[0].h, acc); acc = MFMA(F.A2[1][1], B1l[1].h, acc);  // w1*a1
    acc = MFMA(F.A2[2][0], B0[0].h, acc);  acc = MFMA(F.A2[2][1], B0[1].h, acc);   // w2*a0 (+b2)

    // L3: 5 -> 30
    split5(acc, hi, C0, C1);
    acc = MFMA(F.A3[0][0], C0.h, Z);   acc = MFMA(F.A3[0][1], C1.h, acc);
    acc = MFMA(F.A3[1][0], C0.h, acc); acc = MFMA(F.A3[1][1], C1.h, acc);
    acc = MFMA(F.A3[2][0], C0.h, acc); acc = MFMA(F.A3[2][1], C1.h, acc);

    // L4: 30 -> 5 (no relu on output)
    split30(acc, hi, B0, B1l, B2);
    acc = MFMA(F.A4[0][0], B0[0].h, Z);    acc = MFMA(F.A4[0][1], B0[1].h, acc);
    acc = MFMA(F.A4[0][0], B1l[0].h, acc); acc = MFMA(F.A4[0][1], B1l[1].h, acc);
    acc = MFMA(F.A4[0][0], B2[0].h, acc);  acc = MFMA(F.A4[0][1], B2[1].h, acc);
    acc = MFMA(F.A4[1][0], B0[0].h, acc);  acc = MFMA(F.A4[1][1], B0[1].h, acc);
    acc = MFMA(F.A4[1][0], B1l[0].h, acc); acc = MFMA(F.A4[1][1], B1l[1].h, acc);
    acc = MFMA(F.A4[2][0], B0[0].h, acc);  acc = MFMA(F.A4[2][1], B0[1].h, acc);

    // L5: 5 -> 30
    split5(acc, hi, C0, C1);
    acc = MFMA(F.A5[0][0], C0.h, Z);   acc = MFMA(F.A5[0][1], C1.h, acc);
    acc = MFMA(F.A5[1][0], C0.h, acc); acc = MFMA(F.A5[1][1], C1.h, acc);
    acc = MFMA(F.A5[2][0], C0.h, acc); acc = MFMA(F.A5[2][1], C1.h, acc);

    // L6: 30 -> 2
    split30(acc, hi, B0, B1l, B2);
    acc = MFMA(F.A6[0][0], B0[0].h, Z);    acc = MFMA(F.A6[0][1], B0[1].h, acc);
    acc = MFMA(F.A6[0][0], B1l[0].h, acc); acc = MFMA(F.A6[0][1], B1l[1].h, acc);
    acc = MFMA(F.A6[0][0], B2[0].h, acc);  acc = MFMA(F.A6[0][1], B2[1].h, acc);
    acc = MFMA(F.A6[1][0], B0[0].h, acc);  acc = MFMA(F.A6[1][1], B0[1].h, acc);
    acc = MFMA(F.A6[1][0], B1l[0].h, acc); acc = MFMA(F.A6[1][1], B1l[1].h, acc);
    acc = MFMA(F.A6[2][0], B0[0].h, acc);  acc = MFMA(F.A6[2][1], B0[1].h, acc);

    o0 = acc[0];   // unit 0, lanes 0-31
    o1 = acc[1];   // unit 1, lanes 0-31
}

__global__ __launch_bounds__(256, 1) void mc_hedge_mfma(
    const float* __restrict__ S0, const float* __restrict__ Kv,
    const float* __restrict__ Tv, const float* __restrict__ BM,
    const float* __restrict__ W1, const float* __restrict__ b1,
    const float* __restrict__ W2, const float* __restrict__ b2,
    const float* __restrict__ W3, const float* __restrict__ b3,
    const float* __restrict__ W4, const float* __restrict__ b4,
    const float* __restrict__ W5, const float* __restrict__ b5,
    const float* __restrict__ W6, const float* __restrict__ b6,
    float* __restrict__ out, int Btot)
{
    const int lane = threadIdx.x & 63;
    const int wid  = threadIdx.x >> 6;
    const int pbase = blockIdx.x * 128 + wid * 32;   // 32 paths per wave
    const int p = min(pbase + (lane & 31), Btot - 1);
    const bool hi = lane >= 32;

    Frags F;
    for (int s = 0; s < 3; ++s) F.A1[s] = a1f(W1, b1, s, lane);
    for (int m = 0; m < 3; ++m)
        for (int f = 0; f < 2; ++f) {
            F.A2[m][f] = awide(W2, b2, 5, 5, f, m, lane);
            F.A4[m][f] = awide(W4, b4, 5, 5, f, m, lane);
            F.A6[m][f] = awide(W6, b6, 2, 2, f, m, lane);
            F.A3[m][f] = a5(W3, b3, m, f, lane);
            F.A5[m][f] = a5(W5, b5, m, f, lane);
        }

    f32x16 Z;
#pragma unroll
    for (int i = 0; i < 16; ++i) Z[i] = 0.0f;

    float price = S0[p];
    const float Kk = Kv[p];
    const float T  = Tv[p];
    const float logK = __logf(Kk);
    float hedge = 0.0f;
    const float* bmrow = BM + (size_t)p * NSTEPS;

#pragma unroll 1
    for (int idx = 0; idx < NSTEPS; ++idx) {
        const float time = (float)(idx + 1) / (float)NSTEPS;   // exact at 0.5 / 1.0
        const float docomp = (time <= T) ? 1.0f : 0.0f;
        const float inc = bmrow[idx] * (1.0f / (float)NSTEPS);
        const float tmt = T - time;

        unsigned tT0, tT1, tT2;
        split_pair(time, tmt, tT0, tT1, tT2);   // shared by both evals

        float o0, o1;

        // eval 1: leverage
        float f3 = __logf(price) - logK;
        evalnet(price, f3, tT0, tT1, tT2, hi, F, Z, o0, o1);
        const float lev = __shfl(o0, lane & 31);
        price = price + docomp * lev * price * inc;

        // eval 2: hedge increment
        f3 = __logf(price) - logK;
        evalnet(price, f3, tT0, tT1, tT2, hi, F, Z, o0, o1);
        const float hed = __shfl(o1, lane & 31);
        hedge = hedge + docomp * (hed * inc);
    }

    if (!hi && (pbase + lane) < Btot) {
        const float payoff = fmaxf(price - Kk, 0.0f);
        out[pbase + lane] = payoff - hedge;
    }
}

extern "C" void kernel_launch(void* const* d_in, const int* in_sizes, int n_in,
                              void* d_out, int out_size, void* d_ws, size_t ws_size,
                              hipStream_t stream)
{
    const float* S0 = (const float*)d_in[0];
    const float* Kv = (const float*)d_in[1];
    const float* Tv = (const float*)d_in[2];
    const float* BM = (const float*)d_in[3];
    const float* W1 = (const float*)d_in[4];
    const float* b1 = (const float*)d_in[5];
    const float* W2 = (const float*)d_in[6];
    const float* b2 = (const float*)d_in[7];
    const float* W3 = (const float*)d_in[8];
    const float* b3 = (const float*)d_in[9];
    const float* W4 = (const float*)d_in[10];
    const float* b4 = (const float*)d_in[11];
    const float* W5 = (const float*)d_in[12];
    const float* b5 = (const float*)d_in[13];
    const float* W6 = (const float*)d_in[14];
    const float* b6 = (const float*)d_in[15];

    float* out = (float*)d_out;
    const int B = in_sizes[0];
    const int block = 256;               // 4 waves x 32 paths = 128 paths/block
    const int grid = (B + 127) / 128;

    mc_hedge_mfma<<<grid, block, 0, stream>>>(
        S0, Kv, Tv, BM,
        W1, b1, W2, b2, W3, b3, W4, b4, W5, b5, W6, b6,
        out, B);
}

// Round 8
// 1665.629 us; speedup vs baseline: 1.3460x; 1.1582x over previous
//
#include <hip/hip_runtime.h>

#define NSTEPS 20

typedef short bf16x8 __attribute__((ext_vector_type(8)));
typedef float f32x16 __attribute__((ext_vector_type(16)));

union B8 { bf16x8 h; unsigned u[4]; unsigned short s[8]; };

// RNE f32 -> bf16 bits
__device__ __forceinline__ unsigned short f2bf(float x) {
    unsigned u = __builtin_bit_cast(unsigned, x);
    u += 0x7fffu + ((u >> 16) & 1u);
    return (unsigned short)(u >> 16);
}
__device__ __forceinline__ float bf2f(unsigned short b) {
    return __builtin_bit_cast(float, (unsigned)b << 16);
}
__device__ __forceinline__ unsigned pk(unsigned short lo, unsigned short hi) {
    return (unsigned)lo | ((unsigned)hi << 16);
}
__device__ __forceinline__ unsigned cvtpk(float a, float b) {
    unsigned r;
    asm("v_cvt_pk_bf16_f32 %0, %1, %2" : "=v"(r) : "v"(a), "v"(b));
    return r;
}
__device__ __forceinline__ float lo_f(unsigned w) { return __builtin_bit_cast(float, w << 16); }
__device__ __forceinline__ float hi_f(unsigned w) { return __builtin_bit_cast(float, w & 0xffff0000u); }

#define MFMA(A, B, C) __builtin_amdgcn_mfma_f32_32x32x16_bf16((A), (B), (C), 0, 0, 0)

// 3-limb split (exact to ~2^-26 relative; bf16 => never denormal)
__device__ __forceinline__ void wlimbs(float w, unsigned short& l0, unsigned short& l1, unsigned short& l2) {
    l0 = f2bf(w); float e = w - bf2f(l0);
    l1 = f2bf(e); e -= bf2f(l1);
    l2 = f2bf(e);
}
__device__ __forceinline__ unsigned short pick(int m, unsigned short l0, unsigned short l1, unsigned short l2) {
    return (m == 0) ? l0 : ((m == 1) ? l1 : l2);
}

// ---------- A-fragment builders; k = 16*F_ + 4h + (j&3) + 8*(j>>2) ----------
// All __forceinline__ templates with literal indices: the Frags aggregate must
// never be runtime-indexed (rule #20: runtime-indexed aggregates -> scratch;
// round 7 paid 1.7 GB of HBM scratch traffic for exactly this).

template<int F_, int M>
__device__ __forceinline__ bf16x8 awide(const float* W, const float* bias, int nout, int ld, int lane)
{
    const int u = lane & 31, h = (lane >> 5) & 1;
    B8 r;
#pragma unroll
    for (int j = 0; j < 8; ++j) {
        const int k = 16 * F_ + 4 * h + (j & 3) + 8 * (j >> 2);
        float v = 0.f;
        if (u < nout) {
            if (k < 30) v = W[k * ld + u];
            else if (k == 30) v = bias[u];
        }
        unsigned short l0, l1, l2; wlimbs(v, l0, l1, l2);
        r.s[j] = (short)pick(M, l0, l1, l2);
    }
    return r.h;
}

// 5-input layers (L3/L5); same slot map as round 7.
template<int S, int F_>
__device__ __forceinline__ bf16x8 a5(const float* W, const float* bias, int lane)
{
    const int u = lane & 31, h = (lane >> 5) & 1;
    B8 r;
#pragma unroll
    for (int j = 0; j < 8; ++j) {
        const int k = 16 * F_ + 4 * h + (j & 3) + 8 * (j >> 2);
        unsigned short bits = 0;
        if (u < 30) {
            int in = -1, m = -1;
            if (F_ == 0) {
                if (k < 4)       { in = k; m = S; }
                else if (k == 4) { in = 4; m = S; }
            } else {
                if (k >= 16 && k < 20)      { in = k - 16; m = (S == 0) ? 1 : ((S == 1) ? 0 : -1); }
                else if (k == 20)           { in = 4;      m = (S == 0) ? 1 : ((S == 1) ? 0 : -1); }
                else if (k >= 24 && k < 28) { in = k - 24; m = (S == 0) ? 2 : ((S == 2) ? 0 : -1); }
                else if (k == 21)           { in = 4;      m = (S == 0) ? 2 : ((S == 2) ? 0 : -1); }
            }
            if (in >= 0 && m >= 0) {
                unsigned short l0, l1, l2; wlimbs(W[in * 30 + u], l0, l1, l2);
                bits = pick(m, l0, l1, l2);
            } else if (F_ == 0 && k == 15) {
                unsigned short l0, l1, l2; wlimbs(bias[u], l0, l1, l2);
                bits = pick(S, l0, l1, l2);
            }
        }
        r.s[j] = (short)bits;
    }
    return r.h;
}

// L1; same slot map as round 7.
template<int S>
__device__ __forceinline__ bf16x8 a1f(const float* W1, const float* b1v, int lane)
{
    const int perm[4] = {0, 3, 1, 2};
    const int u = lane & 31, h = (lane >> 5) & 1;
    B8 r;
#pragma unroll
    for (int j = 0; j < 8; ++j) {
        const int k = 4 * h + (j & 3) + 8 * (j >> 2);
        unsigned short bits = 0;
        if (u < 30) {
            int in = -1, m = -1;
            if (k < 4)       { in = k;     m = (S == 0) ? 0 : ((S == 1) ? 1 : 2); }
            else if (k < 8)  { in = k - 4; m = (S == 0) ? 1 : ((S == 1) ? 0 : -1); }
            else if (k < 12) { in = k - 8; m = (S == 0) ? 2 : ((S == 2) ? 0 : -1); }
            if (in >= 0 && m >= 0) {
                unsigned short l0, l1, l2; wlimbs(W1[perm[in] * 30 + u], l0, l1, l2);
                bits = pick(m, l0, l1, l2);
            } else if (k == 12) {
                unsigned short l0, l1, l2; wlimbs(b1v[u], l0, l1, l2);
                bits = pick(S, l0, l1, l2);
            }
        }
        r.s[j] = (short)bits;
    }
    return r.h;
}

// ---------- activation transitions ----------

__device__ __forceinline__ void split_pair(float a, float b,
                                           unsigned& w0, unsigned& w1, unsigned& w2)
{
    w0 = cvtpk(a, b);
    float e0 = a - lo_f(w0), e1 = b - hi_f(w0);
    w1 = cvtpk(e0, e1);
    float f0 = e0 - lo_f(w1), f1 = e1 - hi_f(w1);
    w2 = cvtpk(f0, f1);
}

// 30-wide output -> 3 limb frag-pairs, WITH relu; named outputs (no arrays).
__device__ __forceinline__ void split30(const f32x16& acc, bool hi,
                                        B8& B0a, B8& B0b, B8& B1a, B8& B1b,
                                        B8& B2a, B8& B2b)
{
#pragma unroll
    for (int i = 0; i < 4; ++i) {
        const float a = fmaxf(acc[2 * i], 0.f), b = fmaxf(acc[2 * i + 1], 0.f);
        unsigned w0, w1, w2; split_pair(a, b, w0, w1, w2);
        B0a.u[i] = w0; B1a.u[i] = w1; B2a.u[i] = w2;
    }
#pragma unroll
    for (int i = 0; i < 4; ++i) {
        const float a = fmaxf(acc[8 + 2 * i], 0.f), b = fmaxf(acc[8 + 2 * i + 1], 0.f);
        unsigned w0, w1, w2; split_pair(a, b, w0, w1, w2);
        B0b.u[i] = w0; B1b.u[i] = w1; B2b.u[i] = w2;
    }
    if (hi) { B0b.u[3] = 0x00003F80u; B1b.u[3] = 0u; B2b.u[3] = 0u; }
}

// 5-wide output; NO relu (reference has no nonlinearity on L2/L4 outputs).
__device__ __forceinline__ void split5(const f32x16& acc, bool hi, B8& C0, B8& C1)
{
    const float a0 = acc[0], a1 = acc[1];
    const float a2 = acc[2], a3 = acc[3];
    unsigned p0, p1, p2, q0, q1, q2;
    split_pair(a0, a1, p0, p1, p2);
    split_pair(a2, a3, q0, q1, q2);
    if (!hi) {
        C0.u[0] = p0; C0.u[1] = q0; C0.u[2] = 0; C0.u[3] = 0;
        C1.u[0] = p1; C1.u[1] = q1; C1.u[2] = p2; C1.u[3] = q2;
    } else {
        C0.u[0] = p0 & 0xffffu;
        C0.u[1] = 0; C0.u[2] = 0;
        C0.u[3] = 0x3F800000u;
        C1.u[0] = pk((unsigned short)(p1 & 0xffffu), (unsigned short)(p2 & 0xffffu));
        C1.u[1] = 0; C1.u[2] = 0; C1.u[3] = 0;
    }
}

// Named members only — never indexed at runtime.
struct Frags {
    bf16x8 A1_0, A1_1, A1_2;
    bf16x8 A2_00, A2_01, A2_10, A2_11, A2_20, A2_21;   // [m][f]
    bf16x8 A3_00, A3_01, A3_10, A3_11, A3_20, A3_21;   // [s][f]
    bf16x8 A4_00, A4_01, A4_10, A4_11, A4_20, A4_21;
    bf16x8 A5_00, A5_01, A5_10, A5_11, A5_20, A5_21;
    bf16x8 A6_00, A6_01, A6_10, A6_11, A6_20, A6_21;
};

__device__ __forceinline__ void evalnet(
    float price, float f3, unsigned tT0, unsigned tT1, unsigned tT2,
    bool hi, const Frags& F, const f32x16& Z, float& o0, float& o1)
{
    unsigned pf0, pf1, pf2;
    split_pair(price, f3, pf0, pf1, pf2);
    B8 B;
    if (!hi) { B.u[0] = pf0; B.u[1] = tT0; B.u[2] = pf2; B.u[3] = tT2; }
    else     { B.u[0] = pf1; B.u[1] = tT1; B.u[2] = 0x00003F80u; B.u[3] = 0u; }

    f32x16 acc = MFMA(F.A1_0, B.h, Z);
    acc = MFMA(F.A1_1, B.h, acc);
    acc = MFMA(F.A1_2, B.h, acc);

    B8 B0a, B0b, B1a, B1b, B2a, B2b, C0, C1;

    // L2: 30 -> 5 (no relu on output)
    split30(acc, hi, B0a, B0b, B1a, B1b, B2a, B2b);
    acc = MFMA(F.A2_00, B0a.h, Z);   acc = MFMA(F.A2_01, B0b.h, acc);
    acc = MFMA(F.A2_00, B1a.h, acc); acc = MFMA(F.A2_01, B1b.h, acc);
    acc = MFMA(F.A2_00, B2a.h, acc); acc = MFMA(F.A2_01, B2b.h, acc);
    acc = MFMA(F.A2_10, B0a.h, acc); acc = MFMA(F.A2_11, B0b.h, acc);
    acc = MFMA(F.A2_10, B1a.h, acc); acc = MFMA(F.A2_11, B1b.h, acc);
    acc = MFMA(F.A2_20, B0a.h, acc); acc = MFMA(F.A2_21, B0b.h, acc);

    // L3: 5 -> 30
    split5(acc, hi, C0, C1);
    acc = MFMA(F.A3_00, C0.h, Z);   acc = MFMA(F.A3_01, C1.h, acc);
    acc = MFMA(F.A3_10, C0.h, acc); acc = MFMA(F.A3_11, C1.h, acc);
    acc = MFMA(F.A3_20, C0.h, acc); acc = MFMA(F.A3_21, C1.h, acc);

    // L4: 30 -> 5 (no relu on output)
    split30(acc, hi, B0a, B0b, B1a, B1b, B2a, B2b);
    acc = MFMA(F.A4_00, B0a.h, Z);   acc = MFMA(F.A4_01, B0b.h, acc);
    acc = MFMA(F.A4_00, B1a.h, acc); acc = MFMA(F.A4_01, B1b.h, acc);
    acc = MFMA(F.A4_00, B2a.h, acc); acc = MFMA(F.A4_01, B2b.h, acc);
    acc = MFMA(F.A4_10, B0a.h, acc); acc = MFMA(F.A4_11, B0b.h, acc);
    acc = MFMA(F.A4_10, B1a.h, acc); acc = MFMA(F.A4_11, B1b.h, acc);
    acc = MFMA(F.A4_20, B0a.h, acc); acc = MFMA(F.A4_21, B0b.h, acc);

    // L5: 5 -> 30
    split5(acc, hi, C0, C1);
    acc = MFMA(F.A5_00, C0.h, Z);   acc = MFMA(F.A5_01, C1.h, acc);
    acc = MFMA(F.A5_10, C0.h, acc); acc = MFMA(F.A5_11, C1.h, acc);
    acc = MFMA(F.A5_20, C0.h, acc); acc = MFMA(F.A5_21, C1.h, acc);

    // L6: 30 -> 2
    split30(acc, hi, B0a, B0b, B1a, B1b, B2a, B2b);
    acc = MFMA(F.A6_00, B0a.h, Z);   acc = MFMA(F.A6_01, B0b.h, acc);
    acc = MFMA(F.A6_00, B1a.h, acc); acc = MFMA(F.A6_01, B1b.h, acc);
    acc = MFMA(F.A6_00, B2a.h, acc); acc = MFMA(F.A6_01, B2b.h, acc);
    acc = MFMA(F.A6_10, B0a.h, acc); acc = MFMA(F.A6_11, B0b.h, acc);
    acc = MFMA(F.A6_10, B1a.h, acc); acc = MFMA(F.A6_11, B1b.h, acc);
    acc = MFMA(F.A6_20, B0a.h, acc); acc = MFMA(F.A6_21, B0b.h, acc);

    o0 = acc[0];
    o1 = acc[1];
}

__global__ __launch_bounds__(256, 2) void mc_hedge_mfma(
    const float* __restrict__ S0, const float* __restrict__ Kv,
    const float* __restrict__ Tv, const float* __restrict__ BM,
    const float* __restrict__ W1, const float* __restrict__ b1,
    const float* __restrict__ W2, const float* __restrict__ b2,
    const float* __restrict__ W3, const float* __restrict__ b3,
    const float* __restrict__ W4, const float* __restrict__ b4,
    const float* __restrict__ W5, const float* __restrict__ b5,
    const float* __restrict__ W6, const float* __restrict__ b6,
    float* __restrict__ out, int Btot)
{
    const int lane = threadIdx.x & 63;
    const int wid  = threadIdx.x >> 6;
    const int pbase = blockIdx.x * 128 + wid * 32;   // 32 paths per wave
    const int p = min(pbase + (lane & 31), Btot - 1);
    const bool hi = lane >= 32;

    // Explicit literal-index builds: F must live entirely in VGPRs.
    Frags F;
    F.A1_0 = a1f<0>(W1, b1, lane);
    F.A1_1 = a1f<1>(W1, b1, lane);
    F.A1_2 = a1f<2>(W1, b1, lane);
    F.A2_00 = awide<0,0>(W2, b2, 5, 5, lane); F.A2_01 = awide<1,0>(W2, b2, 5, 5, lane);
    F.A2_10 = awide<0,1>(W2, b2, 5, 5, lane); F.A2_11 = awide<1,1>(W2, b2, 5, 5, lane);
    F.A2_20 = awide<0,2>(W2, b2, 5, 5, lane); F.A2_21 = awide<1,2>(W2, b2, 5, 5, lane);
    F.A3_00 = a5<0,0>(W3, b3, lane); F.A3_01 = a5<0,1>(W3, b3, lane);
    F.A3_10 = a5<1,0>(W3, b3, lane); F.A3_11 = a5<1,1>(W3, b3, lane);
    F.A3_20 = a5<2,0>(W3, b3, lane); F.A3_21 = a5<2,1>(W3, b3, lane);
    F.A4_00 = awide<0,0>(W4, b4, 5, 5, lane); F.A4_01 = awide<1,0>(W4, b4, 5, 5, lane);
    F.A4_10 = awide<0,1>(W4, b4, 5, 5, lane); F.A4_11 = awide<1,1>(W4, b4, 5, 5, lane);
    F.A4_20 = awide<0,2>(W4, b4, 5, 5, lane); F.A4_21 = awide<1,2>(W4, b4, 5, 5, lane);
    F.A5_00 = a5<0,0>(W5, b5, lane); F.A5_01 = a5<0,1>(W5, b5, lane);
    F.A5_10 = a5<1,0>(W5, b5, lane); F.A5_11 = a5<1,1>(W5, b5, lane);
    F.A5_20 = a5<2,0>(W5, b5, lane); F.A5_21 = a5<2,1>(W5, b5, lane);
    F.A6_00 = awide<0,0>(W6, b6, 2, 2, lane); F.A6_01 = awide<1,0>(W6, b6, 2, 2, lane);
    F.A6_10 = awide<0,1>(W6, b6, 2, 2, lane); F.A6_11 = awide<1,1>(W6, b6, 2, 2, lane);
    F.A6_20 = awide<0,2>(W6, b6, 2, 2, lane); F.A6_21 = awide<1,2>(W6, b6, 2, 2, lane);

    f32x16 Z;
#pragma unroll
    for (int i = 0; i < 16; ++i) Z[i] = 0.0f;

    float price = S0[p];
    const float Kk = Kv[p];
    const float T  = Tv[p];
    const float logK = __logf(Kk);
    float hedge = 0.0f;
    const float* bmrow = BM + (size_t)p * NSTEPS;

#pragma unroll 1
    for (int idx = 0; idx < NSTEPS; ++idx) {
        const float time = (float)(idx + 1) / (float)NSTEPS;   // exact at 0.5 / 1.0
        const float docomp = (time <= T) ? 1.0f : 0.0f;
        const float inc = bmrow[idx] * (1.0f / (float)NSTEPS);
        const float tmt = T - time;

        unsigned tT0, tT1, tT2;
        split_pair(time, tmt, tT0, tT1, tT2);

        float o0, o1;

        // eval 1: leverage
        float f3 = __logf(price) - logK;
        evalnet(price, f3, tT0, tT1, tT2, hi, F, Z, o0, o1);
        const float lev = __shfl(o0, lane & 31);
        price = price + docomp * lev * price * inc;

        // eval 2: hedge increment
        f3 = __logf(price) - logK;
        evalnet(price, f3, tT0, tT1, tT2, hi, F, Z, o0, o1);
        const float hed = __shfl(o1, lane & 31);
        hedge = hedge + docomp * (hed * inc);
    }

    if (!hi && (pbase + lane) < Btot) {
        const float payoff = fmaxf(price - Kk, 0.0f);
        out[pbase + lane] = payoff - hedge;
    }
}

extern "C" void kernel_launch(void* const* d_in, const int* in_sizes, int n_in,
                              void* d_out, int out_size, void* d_ws, size_t ws_size,
                              hipStream_t stream)
{
    const float* S0 = (const float*)d_in[0];
    const float* Kv = (const float*)d_in[1];
    const float* Tv = (const float*)d_in[2];
    const float* BM = (const float*)d_in[3];
    const float* W1 = (const float*)d_in[4];
    const float* b1 = (const float*)d_in[5];
    const float* W2 = (const float*)d_in[6];
    const float* b2 = (const float*)d_in[7];
    const float* W3 = (const float*)d_in[8];
    const float* b3 = (const float*)d_in[9];
    const float* W4 = (const float*)d_in[10];
    const float* b4 = (const float*)d_in[11];
    const float* W5 = (const float*)d_in[12];
    const float* b5 = (const float*)d_in[13];
    const float* W6 = (const float*)d_in[14];
    const float* b6 = (const float*)d_in[15];

    float* out = (float*)d_out;
    const int B = in_sizes[0];
    const int block = 256;               // 4 waves x 32 paths = 128 paths/block
    const int grid = (B + 127) / 128;

    mc_hedge_mfma<<<grid, block, 0, stream>>>(
        S0, Kv, Tv, BM,
        W1, b1, W2, b2, W3, b3, W4, b4, W5, b5, W6, b6,
        out, B);
}

// Round 9
// 1341.234 us; speedup vs baseline: 1.6715x; 1.2419x over previous
//
#include <hip/hip_runtime.h>

#define NSTEPS 20

typedef short bf16x8 __attribute__((ext_vector_type(8)));
typedef float f32x16 __attribute__((ext_vector_type(16)));

union B8 { bf16x8 h; unsigned u[4]; unsigned short s[8]; };

// RNE f32 -> bf16 bits
__device__ __forceinline__ unsigned short f2bf(float x) {
    unsigned u = __builtin_bit_cast(unsigned, x);
    u += 0x7fffu + ((u >> 16) & 1u);
    return (unsigned short)(u >> 16);
}
__device__ __forceinline__ float bf2f(unsigned short b) {
    return __builtin_bit_cast(float, (unsigned)b << 16);
}
__device__ __forceinline__ unsigned pk(unsigned short lo, unsigned short hi) {
    return (unsigned)lo | ((unsigned)hi << 16);
}
__device__ __forceinline__ unsigned cvtpk(float a, float b) {
    unsigned r;
    asm("v_cvt_pk_bf16_f32 %0, %1, %2" : "=v"(r) : "v"(a), "v"(b));
    return r;
}
__device__ __forceinline__ float lo_f(unsigned w) { return __builtin_bit_cast(float, w << 16); }
__device__ __forceinline__ float hi_f(unsigned w) { return __builtin_bit_cast(float, w & 0xffff0000u); }

#define MFMA(A, B, C) __builtin_amdgcn_mfma_f32_32x32x16_bf16((A), (B), (C), 0, 0, 0)

// 3-limb split (exact to ~2^-26 relative; bf16 => never denormal)
__device__ __forceinline__ void wlimbs(float w, unsigned short& l0, unsigned short& l1, unsigned short& l2) {
    l0 = f2bf(w); float e = w - bf2f(l0);
    l1 = f2bf(e); e -= bf2f(l1);
    l2 = f2bf(e);
}
__device__ __forceinline__ unsigned short pick(int m, unsigned short l0, unsigned short l1, unsigned short l2) {
    return (m == 0) ? l0 : ((m == 1) ? l1 : l2);
}

// ---------- A-fragment builders; k = 16*F_ + 4h + (j&3) + 8*(j>>2) ----------
// Literal template indices only (rule #20: runtime-indexed aggregates -> scratch).

template<int F_, int M>
__device__ __forceinline__ bf16x8 awide(const float* W, const float* bias, int nout, int ld, int lane)
{
    const int u = lane & 31, h = (lane >> 5) & 1;
    B8 r;
#pragma unroll
    for (int j = 0; j < 8; ++j) {
        const int k = 16 * F_ + 4 * h + (j & 3) + 8 * (j >> 2);
        float v = 0.f;
        if (u < nout) {
            if (k < 30) v = W[k * ld + u];
            else if (k == 30) v = bias[u];
        }
        unsigned short l0, l1, l2; wlimbs(v, l0, l1, l2);
        r.s[j] = (short)pick(M, l0, l1, l2);
    }
    return r.h;
}

// 5-input layers (L3/L5); same slot map as round 8.
template<int S, int F_>
__device__ __forceinline__ bf16x8 a5(const float* W, const float* bias, int lane)
{
    const int u = lane & 31, h = (lane >> 5) & 1;
    B8 r;
#pragma unroll
    for (int j = 0; j < 8; ++j) {
        const int k = 16 * F_ + 4 * h + (j & 3) + 8 * (j >> 2);
        unsigned short bits = 0;
        if (u < 30) {
            int in = -1, m = -1;
            if (F_ == 0) {
                if (k < 4)       { in = k; m = S; }
                else if (k == 4) { in = 4; m = S; }
            } else {
                if (k >= 16 && k < 20)      { in = k - 16; m = (S == 0) ? 1 : ((S == 1) ? 0 : -1); }
                else if (k == 20)           { in = 4;      m = (S == 0) ? 1 : ((S == 1) ? 0 : -1); }
                else if (k >= 24 && k < 28) { in = k - 24; m = (S == 0) ? 2 : ((S == 2) ? 0 : -1); }
                else if (k == 21)           { in = 4;      m = (S == 0) ? 2 : ((S == 2) ? 0 : -1); }
            }
            if (in >= 0 && m >= 0) {
                unsigned short l0, l1, l2; wlimbs(W[in * 30 + u], l0, l1, l2);
                bits = pick(m, l0, l1, l2);
            } else if (F_ == 0 && k == 15) {
                unsigned short l0, l1, l2; wlimbs(bias[u], l0, l1, l2);
                bits = pick(S, l0, l1, l2);
            }
        }
        r.s[j] = (short)bits;
    }
    return r.h;
}

// L1; same slot map as round 8.
template<int S>
__device__ __forceinline__ bf16x8 a1f(const float* W1, const float* b1v, int lane)
{
    const int perm[4] = {0, 3, 1, 2};
    const int u = lane & 31, h = (lane >> 5) & 1;
    B8 r;
#pragma unroll
    for (int j = 0; j < 8; ++j) {
        const int k = 4 * h + (j & 3) + 8 * (j >> 2);
        unsigned short bits = 0;
        if (u < 30) {
            int in = -1, m = -1;
            if (k < 4)       { in = k;     m = (S == 0) ? 0 : ((S == 1) ? 1 : 2); }
            else if (k < 8)  { in = k - 4; m = (S == 0) ? 1 : ((S == 1) ? 0 : -1); }
            else if (k < 12) { in = k - 8; m = (S == 0) ? 2 : ((S == 2) ? 0 : -1); }
            if (in >= 0 && m >= 0) {
                unsigned short l0, l1, l2; wlimbs(W1[perm[in] * 30 + u], l0, l1, l2);
                bits = pick(m, l0, l1, l2);
            } else if (k == 12) {
                unsigned short l0, l1, l2; wlimbs(b1v[u], l0, l1, l2);
                bits = pick(S, l0, l1, l2);
            }
        }
        r.s[j] = (short)bits;
    }
    return r.h;
}

// ---------- activation transitions ----------

__device__ __forceinline__ void split_pair(float a, float b,
                                           unsigned& w0, unsigned& w1, unsigned& w2)
{
    w0 = cvtpk(a, b);
    float e0 = a - lo_f(w0), e1 = b - hi_f(w0);
    w1 = cvtpk(e0, e1);
    float f0 = e0 - lo_f(w1), f1 = e1 - hi_f(w1);
    w2 = cvtpk(f0, f1);
}

// 30-wide output -> 3 limb frag-pairs, WITH relu (L1/L3 outputs are relu'd).
__device__ __forceinline__ void split30(const f32x16& acc, bool hi,
                                        B8& B0a, B8& B0b, B8& B1a, B8& B1b,
                                        B8& B2a, B8& B2b)
{
#pragma unroll
    for (int i = 0; i < 4; ++i) {
        const float a = fmaxf(acc[2 * i], 0.f), b = fmaxf(acc[2 * i + 1], 0.f);
        unsigned w0, w1, w2; split_pair(a, b, w0, w1, w2);
        B0a.u[i] = w0; B1a.u[i] = w1; B2a.u[i] = w2;
    }
#pragma unroll
    for (int i = 0; i < 4; ++i) {
        const float a = fmaxf(acc[8 + 2 * i], 0.f), b = fmaxf(acc[8 + 2 * i + 1], 0.f);
        unsigned w0, w1, w2; split_pair(a, b, w0, w1, w2);
        B0b.u[i] = w0; B1b.u[i] = w1; B2b.u[i] = w2;
    }
    if (hi) { B0b.u[3] = 0x00003F80u; B1b.u[3] = 0u; B2b.u[3] = 0u; }
}

// 5-wide output; NO relu (reference has no nonlinearity on L2/L4 outputs).
__device__ __forceinline__ void split5(const f32x16& acc, bool hi, B8& C0, B8& C1)
{
    const float a0 = acc[0], a1 = acc[1];
    const float a2 = acc[2], a3 = acc[3];
    unsigned p0, p1, p2, q0, q1, q2;
    split_pair(a0, a1, p0, p1, p2);
    split_pair(a2, a3, q0, q1, q2);
    if (!hi) {
        C0.u[0] = p0; C0.u[1] = q0; C0.u[2] = 0; C0.u[3] = 0;
        C1.u[0] = p1; C1.u[1] = q1; C1.u[2] = p2; C1.u[3] = q2;
    } else {
        C0.u[0] = p0 & 0xffffu;
        C0.u[1] = 0; C0.u[2] = 0;
        C0.u[3] = 0x3F800000u;
        C1.u[0] = pk((unsigned short)(p1 & 0xffffu), (unsigned short)(p2 & 0xffffu));
        C1.u[1] = 0; C1.u[2] = 0; C1.u[3] = 0;
    }
}

// Named members only — never indexed at runtime. (L6 handled on VALU now.)
struct Frags {
    bf16x8 A1_0, A1_1, A1_2;
    bf16x8 A2_00, A2_01, A2_10, A2_11, A2_20, A2_21;   // [m][f]
    bf16x8 A3_00, A3_01, A3_10, A3_11, A3_20, A3_21;   // [s][f]
    bf16x8 A4_00, A4_01, A4_10, A4_11, A4_20, A4_21;
    bf16x8 A5_00, A5_01, A5_10, A5_11, A5_20, A5_21;
};

// MLP through L5; returns the L5 pre-relu accumulator (h5 rows per D-layout).
__device__ __forceinline__ f32x16 evalnet5(
    float price, float f3, unsigned tT0, unsigned tT1, unsigned tT2,
    bool hi, const Frags& F, const f32x16& Z)
{
    unsigned pf0, pf1, pf2;
    split_pair(price, f3, pf0, pf1, pf2);
    B8 B;
    if (!hi) { B.u[0] = pf0; B.u[1] = tT0; B.u[2] = pf2; B.u[3] = tT2; }
    else     { B.u[0] = pf1; B.u[1] = tT1; B.u[2] = 0x00003F80u; B.u[3] = 0u; }

    f32x16 acc = MFMA(F.A1_0, B.h, Z);
    acc = MFMA(F.A1_1, B.h, acc);
    acc = MFMA(F.A1_2, B.h, acc);

    B8 B0a, B0b, B1a, B1b, B2a, B2b, C0, C1;

    // L2: 30 -> 5 (no relu on output)
    split30(acc, hi, B0a, B0b, B1a, B1b, B2a, B2b);
    acc = MFMA(F.A2_00, B0a.h, Z);   acc = MFMA(F.A2_01, B0b.h, acc);
    acc = MFMA(F.A2_00, B1a.h, acc); acc = MFMA(F.A2_01, B1b.h, acc);
    acc = MFMA(F.A2_00, B2a.h, acc); acc = MFMA(F.A2_01, B2b.h, acc);
    acc = MFMA(F.A2_10, B0a.h, acc); acc = MFMA(F.A2_11, B0b.h, acc);
    acc = MFMA(F.A2_10, B1a.h, acc); acc = MFMA(F.A2_11, B1b.h, acc);
    acc = MFMA(F.A2_20, B0a.h, acc); acc = MFMA(F.A2_21, B0b.h, acc);

    // L3: 5 -> 30
    split5(acc, hi, C0, C1);
    acc = MFMA(F.A3_00, C0.h, Z);   acc = MFMA(F.A3_01, C1.h, acc);
    acc = MFMA(F.A3_10, C0.h, acc); acc = MFMA(F.A3_11, C1.h, acc);
    acc = MFMA(F.A3_20, C0.h, acc); acc = MFMA(F.A3_21, C1.h, acc);

    // L4: 30 -> 5 (no relu on output)
    split30(acc, hi, B0a, B0b, B1a, B1b, B2a, B2b);
    acc = MFMA(F.A4_00, B0a.h, Z);   acc = MFMA(F.A4_01, B0b.h, acc);
    acc = MFMA(F.A4_00, B1a.h, acc); acc = MFMA(F.A4_01, B1b.h, acc);
    acc = MFMA(F.A4_00, B2a.h, acc); acc = MFMA(F.A4_01, B2b.h, acc);
    acc = MFMA(F.A4_10, B0a.h, acc); acc = MFMA(F.A4_11, B0b.h, acc);
    acc = MFMA(F.A4_10, B1a.h, acc); acc = MFMA(F.A4_11, B1b.h, acc);
    acc = MFMA(F.A4_20, B0a.h, acc); acc = MFMA(F.A4_21, B0b.h, acc);

    // L5: 5 -> 30
    split5(acc, hi, C0, C1);
    acc = MFMA(F.A5_00, C0.h, Z);   acc = MFMA(F.A5_01, C1.h, acc);
    acc = MFMA(F.A5_10, C0.h, acc); acc = MFMA(F.A5_11, C1.h, acc);
    acc = MFMA(F.A5_20, C0.h, acc); acc = MFMA(F.A5_21, C1.h, acc);

    return acc;   // h5 pre-relu; row(r) = (r&3)+8*(r>>2)+4*hi, col = lane&31
}

// amdgpu_waves_per_eu(2,2): pin allocator at exactly 2 waves/EU -> 256-VGPR
// budget. Round 8's (256,2) minimum let the heuristic stop at 128 VGPR and
// spill ~185 MB of scratch (WRITE_SIZE evidence).
__global__ __launch_bounds__(256) __attribute__((amdgpu_waves_per_eu(2, 2)))
void mc_hedge_mfma(
    const float* __restrict__ S0, const float* __restrict__ Kv,
    const float* __restrict__ Tv, const float* __restrict__ BM,
    const float* __restrict__ W1, const float* __restrict__ b1,
    const float* __restrict__ W2, const float* __restrict__ b2,
    const float* __restrict__ W3, const float* __restrict__ b3,
    const float* __restrict__ W4, const float* __restrict__ b4,
    const float* __restrict__ W5, const float* __restrict__ b5,
    const float* __restrict__ W6, const float* __restrict__ b6,
    float* __restrict__ out, int Btot)
{
    const int lane = threadIdx.x & 63;
    const int wid  = threadIdx.x >> 6;
    const int pbase = blockIdx.x * 128 + wid * 32;   // 32 paths per wave
    const int p = min(pbase + (lane & 31), Btot - 1);
    const bool hi = lane >= 32;

    Frags F;
    F.A1_0 = a1f<0>(W1, b1, lane);
    F.A1_1 = a1f<1>(W1, b1, lane);
    F.A1_2 = a1f<2>(W1, b1, lane);
    F.A2_00 = awide<0,0>(W2, b2, 5, 5, lane); F.A2_01 = awide<1,0>(W2, b2, 5, 5, lane);
    F.A2_10 = awide<0,1>(W2, b2, 5, 5, lane); F.A2_11 = awide<1,1>(W2, b2, 5, 5, lane);
    F.A2_20 = awide<0,2>(W2, b2, 5, 5, lane); F.A2_21 = awide<1,2>(W2, b2, 5, 5, lane);
    F.A3_00 = a5<0,0>(W3, b3, lane); F.A3_01 = a5<0,1>(W3, b3, lane);
    F.A3_10 = a5<1,0>(W3, b3, lane); F.A3_11 = a5<1,1>(W3, b3, lane);
    F.A3_20 = a5<2,0>(W3, b3, lane); F.A3_21 = a5<2,1>(W3, b3, lane);
    F.A4_00 = awide<0,0>(W4, b4, 5, 5, lane); F.A4_01 = awide<1,0>(W4, b4, 5, 5, lane);
    F.A4_10 = awide<0,1>(W4, b4, 5, 5, lane); F.A4_11 = awide<1,1>(W4, b4, 5, 5, lane);
    F.A4_20 = awide<0,2>(W4, b4, 5, 5, lane); F.A4_21 = awide<1,2>(W4, b4, 5, 5, lane);
    F.A5_00 = a5<0,0>(W5, b5, lane); F.A5_01 = a5<0,1>(W5, b5, lane);
    F.A5_10 = a5<1,0>(W5, b5, lane); F.A5_11 = a5<1,1>(W5, b5, lane);
    F.A5_20 = a5<2,0>(W5, b5, lane); F.A5_21 = a5<2,1>(W5, b5, lane);

    // L6 weights on VALU: per-lane-half selected column weights, hoisted out
    // of the time loop. Row r holds unit row(r) = (r&3)+8*(r>>2)+4*hi.
    // Rows 30/31 (hi half, r=14,15) are padding -> weight 0 (avoid OOB read).
    f32x16 wv0, wv1;
#pragma unroll
    for (int r = 0; r < 16; ++r) {
        const int row0 = (r & 3) + 8 * (r >> 2);
        const int row1 = row0 + 4;
        const float w00 = W6[row0 * 2 + 0];
        const float w01 = W6[row0 * 2 + 1];
        const float w10 = (row1 < 30) ? W6[row1 * 2 + 0] : 0.f;
        const float w11 = (row1 < 30) ? W6[row1 * 2 + 1] : 0.f;
        wv0[r] = hi ? w10 : w00;
        wv1[r] = hi ? w11 : w01;
    }
    const float b60 = b6[0], b61 = b6[1];

    f32x16 Z;
#pragma unroll
    for (int i = 0; i < 16; ++i) Z[i] = 0.0f;

    float price = S0[p];
    const float Kk = Kv[p];
    const float T  = Tv[p];
    const float logK = __logf(Kk);
    float hedge = 0.0f;
    const float* bmrow = BM + (size_t)p * NSTEPS;

#pragma unroll 1
    for (int idx = 0; idx < NSTEPS; ++idx) {
        const float time = (float)(idx + 1) / (float)NSTEPS;   // exact at 0.5 / 1.0
        const float docomp = (time <= T) ? 1.0f : 0.0f;
        const float inc = bmrow[idx] * (1.0f / (float)NSTEPS);
        const float tmt = T - time;

        unsigned tT0, tT1, tT2;
        split_pair(time, tmt, tT0, tT1, tT2);

        // eval 1: leverage = net(feats(price))[0]
        float f3 = __logf(price) - logK;
        f32x16 a5v = evalnet5(price, f3, tT0, tT1, tT2, hi, F, Z);
        float part = 0.f;
#pragma unroll
        for (int r = 0; r < 16; ++r) part = fmaf(fmaxf(a5v[r], 0.f), wv0[r], part);
        part += __shfl_xor(part, 32);
        const float lev = part + b60;           // identical on both lane halves
        price = price + docomp * lev * price * inc;

        // eval 2: hedge increment = net(feats(price_new))[1] * inc
        f3 = __logf(price) - logK;
        a5v = evalnet5(price, f3, tT0, tT1, tT2, hi, F, Z);
        part = 0.f;
#pragma unroll
        for (int r = 0; r < 16; ++r) part = fmaf(fmaxf(a5v[r], 0.f), wv1[r], part);
        part += __shfl_xor(part, 32);
        const float hed = (part + b61) * inc;
        hedge = hedge + docomp * hed;
    }

    if (!hi && (pbase + lane) < Btot) {
        const float payoff = fmaxf(price - Kk, 0.0f);
        out[pbase + lane] = payoff - hedge;
    }
}

extern "C" void kernel_launch(void* const* d_in, const int* in_sizes, int n_in,
                              void* d_out, int out_size, void* d_ws, size_t ws_size,
                              hipStream_t stream)
{
    const float* S0 = (const float*)d_in[0];
    const float* Kv = (const float*)d_in[1];
    const float* Tv = (const float*)d_in[2];
    const float* BM = (const float*)d_in[3];
    const float* W1 = (const float*)d_in[4];
    const float* b1 = (const float*)d_in[5];
    const float* W2 = (const float*)d_in[6];
    const float* b2 = (const float*)d_in[7];
    const float* W3 = (const float*)d_in[8];
    const float* b3 = (const float*)d_in[9];
    const float* W4 = (const float*)d_in[10];
    const float* b4 = (const float*)d_in[11];
    const float* W5 = (const float*)d_in[12];
    const float* b5 = (const float*)d_in[13];
    const float* W6 = (const float*)d_in[14];
    const float* b6 = (const float*)d_in[15];

    float* out = (float*)d_out;
    const int B = in_sizes[0];
    const int block = 256;               // 4 waves x 32 paths = 128 paths/block
    const int grid = (B + 127) / 128;

    mc_hedge_mfma<<<grid, block, 0, stream>>>(
        S0, Kv, Tv, BM,
        W1, b1, W2, b2, W3, b3, W4, b4, W5, b5, W6, b6,
        out, B);
}